// Round 1
// baseline (990.711 us; speedup 1.0000x reference)
//
#include <hip/hip_runtime.h>

#define N_HP 49152
#define N_DST 50000
#define NE 400000
#define T_OUT 4
#define H 64
#define HID 128

// ---------------- degree histograms ----------------
__global__ __launch_bounds__(256) void k_hist(const int* __restrict__ src_idx,
                                              const int* __restrict__ dst_idx,
                                              int* __restrict__ cnt_src,
                                              int* __restrict__ cnt_dst) {
    int i = blockIdx.x * 256 + threadIdx.x;
    if (i >= 4 * NE) return;
    int tt = i / NE;
    atomicAdd(&cnt_src[tt * N_HP + src_idx[i]], 1);
    atomicAdd(&cnt_dst[tt * N_DST + dst_idx[i]], 1);
}

__global__ __launch_bounds__(256) void k_rsout(const int* __restrict__ cnt_src,
                                               float* __restrict__ rs_out) {
    int i = blockIdx.x * 256 + threadIdx.x;
    if (i >= 4 * N_HP) return;
    int c = cnt_src[i];
    rs_out[i] = rsqrtf((float)(c > 1 ? c : 1));
}

// exclusive scan of cnt_dst per tt (one block per tt) + rs_in
__global__ __launch_bounds__(1024) void k_scan(const int* __restrict__ cnt_dst,
                                               int* __restrict__ offs,
                                               float* __restrict__ rs_in) {
    int tt = blockIdx.x;
    const int* c = cnt_dst + tt * N_DST;
    int* o = offs + tt * N_DST;
    float* r = rs_in + tt * N_DST;
    __shared__ int sh[1024];
    const int CH = (N_DST + 1023) / 1024;  // 49
    int start = threadIdx.x * CH;
    int end = start + CH; if (end > N_DST) end = N_DST;
    int sum = 0;
    for (int i = start; i < end; ++i) sum += c[i];
    sh[threadIdx.x] = sum;
    __syncthreads();
    for (int off = 1; off < 1024; off <<= 1) {
        int add = (threadIdx.x >= off) ? sh[threadIdx.x - off] : 0;
        __syncthreads();
        sh[threadIdx.x] += add;
        __syncthreads();
    }
    int run = sh[threadIdx.x] - sum;  // exclusive prefix of this thread's chunk
    for (int i = start; i < end; ++i) {
        o[i] = run;
        run += c[i];
        int v = c[i];
        r[i] = rsqrtf((float)(v > 1 ? v : 1));
    }
}

__global__ __launch_bounds__(256) void k_fill(const int* __restrict__ src_idx,
                                              const int* __restrict__ dst_idx,
                                              const int* __restrict__ offs,
                                              int* __restrict__ fill,
                                              int* __restrict__ esrc) {
    int i = blockIdx.x * 256 + threadIdx.x;
    if (i >= 4 * NE) return;
    int tt = i / NE;
    int d = dst_idx[i];
    int pos = offs[tt * N_DST + d] + atomicAdd(&fill[tt * N_DST + d], 1);
    esrc[tt * NE + pos] = src_idx[i];
}

// ---------------- fused aggregate + conv matmul + leaky_relu, all 4 t at once ----
// one wave per dst node; lane l accumulates (t = l>>4, h = (l&15)*4 .. +3) via float4
__global__ __launch_bounds__(256) void k_space1(
    const float* __restrict__ x, const int* __restrict__ esrc,
    const int* __restrict__ offs, const int* __restrict__ cnt_dst,
    const float* __restrict__ rs_out, const float* __restrict__ rs_in,
    const float* __restrict__ conv_W, const float* __restrict__ conv_b,
    float* __restrict__ space1) {
    const int wave = threadIdx.x >> 6, lane = threadIdx.x & 63;
    const int dst = blockIdx.x * 4 + wave;   // grid exact: N_DST/4 blocks
    const int t_l = lane >> 4;
    const int h0 = (lane & 15) << 2;
    __shared__ float agg_sh[4][4][H];        // [wave][t][h]
    float sp0 = 0.f, sp1 = 0.f, sp2 = 0.f, sp3 = 0.f;
    const float4* x4 = (const float4*)x;     // row src = 64 float4
    for (int tt = 0; tt < 4; ++tt) {
        const int off = offs[tt * N_DST + dst];
        const int n = cnt_dst[tt * N_DST + dst];
        const int* ep = esrc + tt * NE + off;
        const float* rso = rs_out + tt * N_HP;
        float4 a0 = make_float4(0.f, 0.f, 0.f, 0.f);
        float4 a1 = make_float4(0.f, 0.f, 0.f, 0.f);
        int e = 0;
        for (; e + 2 <= n; e += 2) {     // 2-deep pipeline: two rows in flight
            int s0 = ep[e], s1 = ep[e + 1];
            float r0 = rso[s0], r1 = rso[s1];
            float4 v0 = x4[s0 * 64 + lane];
            float4 v1 = x4[s1 * 64 + lane];
            a0.x += v0.x * r0; a0.y += v0.y * r0; a0.z += v0.z * r0; a0.w += v0.w * r0;
            a1.x += v1.x * r1; a1.y += v1.y * r1; a1.z += v1.z * r1; a1.w += v1.w * r1;
        }
        if (e < n) {
            int s0 = ep[e];
            float r0 = rso[s0];
            float4 v0 = x4[s0 * 64 + lane];
            a0.x += v0.x * r0; a0.y += v0.y * r0; a0.z += v0.z * r0; a0.w += v0.w * r0;
        }
        float ri = rs_in[tt * N_DST + dst];
        float4 acc = make_float4((a0.x + a1.x) * ri, (a0.y + a1.y) * ri,
                                 (a0.z + a1.z) * ri, (a0.w + a1.w) * ri);
        *(float4*)&agg_sh[wave][t_l][h0] = acc;
        __syncthreads();
        const float* W = conv_W + tt * H * H;
        float m0 = 0.f, m1 = 0.f, m2 = 0.f, m3 = 0.f;
#pragma unroll 8
        for (int h = 0; h < H; ++h) {
            float w = W[h * H + lane];
            m0 += agg_sh[wave][0][h] * w;
            m1 += agg_sh[wave][1][h] * w;
            m2 += agg_sh[wave][2][h] * w;
            m3 += agg_sh[wave][3][h] * w;
        }
        float b = conv_b[tt * H + lane];
        m0 += b; m1 += b; m2 += b; m3 += b;
        sp0 += m0 > 0.f ? m0 : 0.01f * m0;
        sp1 += m1 > 0.f ? m1 : 0.01f * m1;
        sp2 += m2 > 0.f ? m2 : 0.01f * m2;
        sp3 += m3 > 0.f ? m3 : 0.01f * m3;
        __syncthreads();
    }
    space1[(0 * N_DST + dst) * H + lane] = sp0;
    space1[(1 * N_DST + dst) * H + lane] = sp1;
    space1[(2 * N_DST + dst) * H + lane] = sp2;
    space1[(3 * N_DST + dst) * H + lane] = sp3;
}

// ---------------- attention + decode for one t (wave per node) ----------------
__global__ __launch_bounds__(256) void k_att(
    const float* __restrict__ sp1, const float* __restrict__ prev,
    const float* __restrict__ lin_W, const float* __restrict__ lin_b,
    const float* __restrict__ W1, const float* __restrict__ b1,
    const float* __restrict__ W2, const float* __restrict__ b2,
    const float* __restrict__ dec_W, const float* __restrict__ dec_b,
    float* __restrict__ out_t) {
    __shared__ float sW1[H * HID];   // 32 KB
    __shared__ float sbuf[4][2][H];
    const int wave = threadIdx.x >> 6, lane = threadIdx.x & 63;
    const int node = blockIdx.x * 4 + wave;  // grid exact
    for (int i = threadIdx.x; i < H * HID; i += 256) sW1[i] = W1[i];
    float s1v = sp1[node * H + lane];
    float s2v = prev[node] * lin_W[lane] + lin_b[lane];
    sbuf[wave][0][lane] = s1v;
    sbuf[wave][1][lane] = s2v;
    __syncthreads();
    float logit0 = 0.f, logit1 = 0.f;
    for (int k = 0; k < 2; ++k) {
        const float* sv = sbuf[wave][k];
        float acc = 0.f;
        for (int jj = 0; jj < 2; ++jj) {
            int j = lane + jj * 64;
            float d = b1[j];
#pragma unroll 8
            for (int h = 0; h < H; ++h) d += sv[h] * sW1[h * HID + j];
            acc += tanhf(d) * W2[j];
        }
        for (int o = 32; o; o >>= 1) acc += __shfl_xor(acc, o);
        if (k == 0) logit0 = acc + b2[0]; else logit1 = acc + b2[0];
    }
    float mx = fmaxf(logit0, logit1);
    float e0 = expf(logit0 - mx), e1 = expf(logit1 - mx);
    float inv = 1.f / (e0 + e1);
    float st = (e0 * inv) * s1v + (e1 * inv) * s2v;
    float o = st * dec_W[lane];
    for (int off = 32; off; off >>= 1) o += __shfl_xor(o, off);
    if (lane == 0) out_t[node] = o + dec_b[0];
}

extern "C" void kernel_launch(void* const* d_in, const int* in_sizes, int n_in,
                              void* d_out, int out_size, void* d_ws, size_t ws_size,
                              hipStream_t stream) {
    const float* x      = (const float*)d_in[0];
    const float* prev0  = (const float*)d_in[1];
    const float* conv_W = (const float*)d_in[2];
    const float* conv_b = (const float*)d_in[3];
    const float* lin_W  = (const float*)d_in[4];
    const float* lin_b  = (const float*)d_in[5];
    const float* att_W1 = (const float*)d_in[6];
    const float* att_b1 = (const float*)d_in[7];
    const float* att_W2 = (const float*)d_in[8];
    const float* att_b2 = (const float*)d_in[9];
    const float* dec_W  = (const float*)d_in[10];
    const float* dec_b  = (const float*)d_in[11];
    const int* src_idx  = (const int*)d_in[12];
    const int* dst_idx  = (const int*)d_in[13];
    float* out = (float*)d_out;

    char* p = (char*)d_ws;
    auto alloc = [&](size_t bytes) {
        char* q = p;
        p += (bytes + 255) & ~(size_t)255;
        return q;
    };
    int*   cnt_src = (int*)alloc((size_t)4 * N_HP * 4);
    int*   cnt_dst = (int*)alloc((size_t)4 * N_DST * 4);
    int*   fill    = (int*)alloc((size_t)4 * N_DST * 4);
    int*   offs    = (int*)alloc((size_t)4 * N_DST * 4);
    float* rs_out  = (float*)alloc((size_t)4 * N_HP * 4);
    float* rs_in   = (float*)alloc((size_t)4 * N_DST * 4);
    int*   esrc    = (int*)alloc((size_t)4 * NE * 4);
    float* space1  = (float*)alloc((size_t)4 * N_DST * H * 4);

    // zero cnt_src + cnt_dst + fill (contiguous, 256-aligned sizes)
    hipMemsetAsync(cnt_src, 0, (size_t)((char*)offs - (char*)cnt_src), stream);

    k_hist<<<(4 * NE + 255) / 256, 256, 0, stream>>>(src_idx, dst_idx, cnt_src, cnt_dst);
    k_rsout<<<(4 * N_HP + 255) / 256, 256, 0, stream>>>(cnt_src, rs_out);
    k_scan<<<4, 1024, 0, stream>>>(cnt_dst, offs, rs_in);
    k_fill<<<(4 * NE + 255) / 256, 256, 0, stream>>>(src_idx, dst_idx, offs, fill, esrc);
    k_space1<<<N_DST / 4, 256, 0, stream>>>(x, esrc, offs, cnt_dst, rs_out, rs_in,
                                            conv_W, conv_b, space1);
    for (int t = 0; t < 4; ++t) {
        const float* prev = (t == 0) ? prev0 : (out + (size_t)(t - 1) * N_DST);
        k_att<<<N_DST / 4, 256, 0, stream>>>(space1 + (size_t)t * N_DST * H, prev,
                                             lin_W, lin_b, att_W1, att_b1, att_W2, att_b2,
                                             dec_W, dec_b, out + (size_t)t * N_DST);
    }
}

// Round 2
// 749.598 us; speedup vs baseline: 1.3217x; 1.3217x over previous
//
#include <hip/hip_runtime.h>

#define N_HP 49152
#define N_DST 50000
#define NE 400000
#define H 64
#define HID 128

// ---------------- degree histograms ----------------
__global__ __launch_bounds__(256) void k_hist(const int* __restrict__ src_idx,
                                              const int* __restrict__ dst_idx,
                                              int* __restrict__ cnt_src,
                                              int* __restrict__ cnt_dst) {
    int i = blockIdx.x * 256 + threadIdx.x;
    if (i >= 4 * NE) return;
    int tt = i / NE;
    atomicAdd(&cnt_src[tt * N_HP + src_idx[i]], 1);
    atomicAdd(&cnt_dst[tt * N_DST + dst_idx[i]], 1);
}

__global__ __launch_bounds__(256) void k_rsout(const int* __restrict__ cnt_src,
                                               float* __restrict__ rs_out) {
    int i = blockIdx.x * 256 + threadIdx.x;
    if (i >= 4 * N_HP) return;
    int c = cnt_src[i];
    rs_out[i] = rsqrtf((float)(c > 1 ? c : 1));
}

// exclusive scan of cnt_dst per tt (one block per tt) + rs_in
__global__ __launch_bounds__(1024) void k_scan(const int* __restrict__ cnt_dst,
                                               int* __restrict__ offs,
                                               float* __restrict__ rs_in) {
    int tt = blockIdx.x;
    const int* c = cnt_dst + tt * N_DST;
    int* o = offs + tt * N_DST;
    float* r = rs_in + tt * N_DST;
    __shared__ int sh[1024];
    const int CH = (N_DST + 1023) / 1024;  // 49
    int start = threadIdx.x * CH;
    int end = start + CH; if (end > N_DST) end = N_DST;
    int sum = 0;
    for (int i = start; i < end; ++i) sum += c[i];
    sh[threadIdx.x] = sum;
    __syncthreads();
    for (int off = 1; off < 1024; off <<= 1) {
        int add = (threadIdx.x >= off) ? sh[threadIdx.x - off] : 0;
        __syncthreads();
        sh[threadIdx.x] += add;
        __syncthreads();
    }
    int run = sh[threadIdx.x] - sum;  // exclusive prefix of this thread's chunk
    for (int i = start; i < end; ++i) {
        o[i] = run;
        run += c[i];
        int v = c[i];
        r[i] = rsqrtf((float)(v > 1 ? v : 1));
    }
}

__global__ __launch_bounds__(256) void k_fill(const int* __restrict__ src_idx,
                                              const int* __restrict__ dst_idx,
                                              const int* __restrict__ offs,
                                              int* __restrict__ fill,
                                              int* __restrict__ esrc) {
    int i = blockIdx.x * 256 + threadIdx.x;
    if (i >= 4 * NE) return;
    int tt = i / NE;
    int d = dst_idx[i];
    int pos = offs[tt * N_DST + d] + atomicAdd(&fill[tt * N_DST + d], 1);
    esrc[tt * NE + pos] = src_idx[i];
}

// ---------------- attention precompute: collapse the prev-dependent path ----
// c1[j] = lin_W . W1[:,j];  c0[j] = lin_b . W1[:,j] + b1[j]
// e1 = lin_W . dec_W;       e0 = lin_b . dec_W
__global__ __launch_bounds__(128) void k_pre(const float* __restrict__ lin_W,
                                             const float* __restrict__ lin_b,
                                             const float* __restrict__ W1,
                                             const float* __restrict__ b1,
                                             const float* __restrict__ dec_W,
                                             float* __restrict__ attc) {
    int j = threadIdx.x;
    float c1 = 0.f, c0 = 0.f;
    for (int h = 0; h < H; ++h) {
        c1 += lin_W[h] * W1[h * HID + j];
        c0 += lin_b[h] * W1[h * HID + j];
    }
    attc[j] = c1;
    attc[HID + j] = c0 + b1[j];
    if (j == 0) {
        float e1 = 0.f, e0 = 0.f;
        for (int h = 0; h < H; ++h) { e1 += lin_W[h] * dec_W[h]; e0 += lin_b[h] * dec_W[h]; }
        attc[2 * HID] = e1;
        attc[2 * HID + 1] = e0;
    }
}

// ---------------- fully fused: gather + conv + leaky + 4-step attention chain ----
// one wave per dst node; 8 waves / 512-thread block
__global__ __launch_bounds__(512) void k_fused(
    const float* __restrict__ x, const int* __restrict__ esrc,
    const int* __restrict__ offs, const int* __restrict__ cnt_dst,
    const float* __restrict__ rs_out, const float* __restrict__ rs_in,
    const float* __restrict__ conv_W, const float* __restrict__ conv_b,
    const float* __restrict__ prev0,
    const float* __restrict__ W1, const float* __restrict__ b1,
    const float* __restrict__ W2, const float* __restrict__ b2,
    const float* __restrict__ dec_W, const float* __restrict__ dec_b,
    const float* __restrict__ attc,
    float* __restrict__ out) {
    __shared__ float sW1[H * HID];        // 32 KB, [h][j]
    __shared__ float sC[2 * HID + 2];
    __shared__ float agg[8][H][4];        // per-wave [h][t], 8 KB
    __shared__ float sb[8][H];            // per-wave s1 broadcast, 2 KB
    const int wave = threadIdx.x >> 6, lane = threadIdx.x & 63;
    const int dst = blockIdx.x * 8 + wave;   // grid exact: N_DST/8
    for (int i = threadIdx.x; i < H * HID; i += 512) sW1[i] = W1[i];
    for (int i = threadIdx.x; i < 2 * HID + 2; i += 512) sC[i] = attc[i];
    __syncthreads();   // only block-wide barrier

    const float4* x4 = (const float4*)x;     // x row = 64 float4 (t = c>>4, h = (c&15)*4+i)
    const int t_l = lane >> 4;
    const int h0 = (lane & 15) << 2;
    float sp0 = 0.f, sp1 = 0.f, sp2 = 0.f, sp3 = 0.f;

    for (int tt = 0; tt < 4; ++tt) {
        const int off = offs[tt * N_DST + dst];
        const int n = cnt_dst[tt * N_DST + dst];
        const int* ep = esrc + tt * NE + off;
        const float* rso = rs_out + tt * N_HP;
        float4 a0 = make_float4(0.f, 0.f, 0.f, 0.f);
        float4 a1 = make_float4(0.f, 0.f, 0.f, 0.f);
        float4 a2 = make_float4(0.f, 0.f, 0.f, 0.f);
        float4 a3 = make_float4(0.f, 0.f, 0.f, 0.f);
        int e = 0;
        for (; e + 4 <= n; e += 4) {   // 4 rows in flight
            int s0 = ep[e], s1 = ep[e + 1], s2 = ep[e + 2], s3 = ep[e + 3];
            float r0 = rso[s0], r1 = rso[s1], r2 = rso[s2], r3 = rso[s3];
            float4 v0 = x4[s0 * 64 + lane];
            float4 v1 = x4[s1 * 64 + lane];
            float4 v2 = x4[s2 * 64 + lane];
            float4 v3 = x4[s3 * 64 + lane];
            a0.x += v0.x * r0; a0.y += v0.y * r0; a0.z += v0.z * r0; a0.w += v0.w * r0;
            a1.x += v1.x * r1; a1.y += v1.y * r1; a1.z += v1.z * r1; a1.w += v1.w * r1;
            a2.x += v2.x * r2; a2.y += v2.y * r2; a2.z += v2.z * r2; a2.w += v2.w * r2;
            a3.x += v3.x * r3; a3.y += v3.y * r3; a3.z += v3.z * r3; a3.w += v3.w * r3;
        }
        for (; e < n; ++e) {
            int s0 = ep[e];
            float r0 = rso[s0];
            float4 v0 = x4[s0 * 64 + lane];
            a0.x += v0.x * r0; a0.y += v0.y * r0; a0.z += v0.z * r0; a0.w += v0.w * r0;
        }
        float ri = rs_in[tt * N_DST + dst];
        float ax = (a0.x + a1.x + a2.x + a3.x) * ri;
        float ay = (a0.y + a1.y + a2.y + a3.y) * ri;
        float az = (a0.z + a1.z + a2.z + a3.z) * ri;
        float aw = (a0.w + a1.w + a2.w + a3.w) * ri;
        // transposed store: agg[h][t]  (per-wave only -> no block barrier needed)
        agg[wave][h0 + 0][t_l] = ax;
        agg[wave][h0 + 1][t_l] = ay;
        agg[wave][h0 + 2][t_l] = az;
        agg[wave][h0 + 3][t_l] = aw;
        const float* W = conv_W + tt * H * H;
        float m0 = 0.f, m1 = 0.f, m2 = 0.f, m3 = 0.f;
#pragma unroll 8
        for (int h = 0; h < H; ++h) {
            float w = W[h * H + lane];
            float4 a = *(const float4*)&agg[wave][h][0];   // ds_read_b128, broadcast
            m0 += a.x * w; m1 += a.y * w; m2 += a.z * w; m3 += a.w * w;
        }
        float b = conv_b[tt * H + lane];
        m0 += b; m1 += b; m2 += b; m3 += b;
        sp0 += m0 > 0.f ? m0 : 0.01f * m0;
        sp1 += m1 > 0.f ? m1 : 0.01f * m1;
        sp2 += m2 > 0.f ? m2 : 0.01f * m2;
        sp3 += m3 > 0.f ? m3 : 0.01f * m3;
    }

    // ---- in-wave 4-step attention/decode chain ----
    float prev = prev0[dst];
    const float b1a = b1[lane], b1b = b1[lane + 64];
    const float w2a = W2[lane], w2b = W2[lane + 64];
    const float c1a = sC[lane], c1b = sC[lane + 64];
    const float c0a = sC[HID + lane], c0b = sC[HID + lane + 64];
    const float e1s = sC[2 * HID], e0s = sC[2 * HID + 1];
    const float decw = dec_W[lane];
    const float b2s = b2[0], decb = dec_b[0];
    float spt[4] = {sp0, sp1, sp2, sp3};
#pragma unroll
    for (int t = 0; t < 4; ++t) {
        float s1v = spt[t];
        sb[wave][lane] = s1v;      // per-wave broadcast buffer
        float d0 = 0.f, d1 = 0.f;
#pragma unroll 8
        for (int h = 0; h < H; ++h) {
            float s = sb[wave][h];
            d0 += s * sW1[h * HID + lane];
            d1 += s * sW1[h * HID + lane + 64];
        }
        float p0 = tanhf(d0 + b1a) * w2a + tanhf(d1 + b1b) * w2b;       // logit0 partial
        float p1 = tanhf(prev * c1a + c0a) * w2a + tanhf(prev * c1b + c0b) * w2b; // logit1 partial
        float p2 = s1v * decw;                                          // s1 . dec_W partial
        for (int o = 32; o; o >>= 1) {
            p0 += __shfl_xor(p0, o);
            p1 += __shfl_xor(p1, o);
            p2 += __shfl_xor(p2, o);
        }
        float l0 = p0 + b2s, l1 = p1 + b2s;
        float mx = fmaxf(l0, l1);
        float ea = expf(l0 - mx), eb = expf(l1 - mx);
        float inv = 1.f / (ea + eb);
        float s2d = prev * e1s + e0s;              // s2 . dec_W as scalar fn of prev
        float ov = (ea * p2 + eb * s2d) * inv + decb;
        prev = ov;
        if (lane == 0) out[t * N_DST + dst] = ov;
    }
}

extern "C" void kernel_launch(void* const* d_in, const int* in_sizes, int n_in,
                              void* d_out, int out_size, void* d_ws, size_t ws_size,
                              hipStream_t stream) {
    const float* x      = (const float*)d_in[0];
    const float* prev0  = (const float*)d_in[1];
    const float* conv_W = (const float*)d_in[2];
    const float* conv_b = (const float*)d_in[3];
    const float* lin_W  = (const float*)d_in[4];
    const float* lin_b  = (const float*)d_in[5];
    const float* att_W1 = (const float*)d_in[6];
    const float* att_b1 = (const float*)d_in[7];
    const float* att_W2 = (const float*)d_in[8];
    const float* att_b2 = (const float*)d_in[9];
    const float* dec_W  = (const float*)d_in[10];
    const float* dec_b  = (const float*)d_in[11];
    const int* src_idx  = (const int*)d_in[12];
    const int* dst_idx  = (const int*)d_in[13];
    float* out = (float*)d_out;

    char* p = (char*)d_ws;
    auto alloc = [&](size_t bytes) {
        char* q = p;
        p += (bytes + 255) & ~(size_t)255;
        return q;
    };
    int*   cnt_src = (int*)alloc((size_t)4 * N_HP * 4);
    int*   cnt_dst = (int*)alloc((size_t)4 * N_DST * 4);
    int*   fill    = (int*)alloc((size_t)4 * N_DST * 4);
    int*   offs    = (int*)alloc((size_t)4 * N_DST * 4);
    float* rs_out  = (float*)alloc((size_t)4 * N_HP * 4);
    float* rs_in   = (float*)alloc((size_t)4 * N_DST * 4);
    int*   esrc    = (int*)alloc((size_t)4 * NE * 4);
    float* attc    = (float*)alloc((size_t)(2 * HID + 2) * 4);

    // zero cnt_src + cnt_dst + fill (contiguous, 256-aligned sizes)
    hipMemsetAsync(cnt_src, 0, (size_t)((char*)offs - (char*)cnt_src), stream);

    k_hist<<<(4 * NE + 255) / 256, 256, 0, stream>>>(src_idx, dst_idx, cnt_src, cnt_dst);
    k_rsout<<<(4 * N_HP + 255) / 256, 256, 0, stream>>>(cnt_src, rs_out);
    k_scan<<<4, 1024, 0, stream>>>(cnt_dst, offs, rs_in);
    k_fill<<<(4 * NE + 255) / 256, 256, 0, stream>>>(src_idx, dst_idx, offs, fill, esrc);
    k_pre<<<1, 128, 0, stream>>>(lin_W, lin_b, att_W1, att_b1, dec_W, attc);
    k_fused<<<N_DST / 8, 512, 0, stream>>>(x, esrc, offs, cnt_dst, rs_out, rs_in,
                                           conv_W, conv_b, prev0,
                                           att_W1, att_b1, att_W2, att_b2,
                                           dec_W, dec_b, attc, out);
}